// Round 1
// baseline (1333.766 us; speedup 1.0000x reference)
//
#include <hip/hip_runtime.h>
#include <cstdint>

#define B_  32
#define S_  512
#define H_  768
#define V_  30522
#define NT_ 24          // N_UPDATE * MAX_LEN sequential steps
#define H3  2304

typedef unsigned short ushort_t;
typedef __attribute__((ext_vector_type(8))) short bf16x8;
typedef __attribute__((ext_vector_type(4))) float f32x4;

__device__ __forceinline__ ushort_t f2bf(float f){
  union { float f; unsigned u; } v; v.f = f;
  unsigned r = v.u + 0x7fffu + ((v.u >> 16) & 1u);
  return (ushort_t)(r >> 16);
}

// ---------------- fp32 -> bf16 cast (vector x4) ----------------
__global__ void k_cast_bf16(const float* __restrict__ src, ushort_t* __restrict__ dst, int n4){
  int i = blockIdx.x * 256 + threadIdx.x;
  if (i >= n4) return;
  float4 v = ((const float4*)src)[i];
  uint2 o;
  o.x = (unsigned)f2bf(v.x) | ((unsigned)f2bf(v.y) << 16);
  o.y = (unsigned)f2bf(v.z) | ((unsigned)f2bf(v.w) << 16);
  ((uint2*)dst)[i] = o;
}

// ---------------- build GRU inputs W_all[t][b][k] ----------------
__global__ void k_build_wall(const float* __restrict__ dec, const float* __restrict__ embed,
                             const int* __restrict__ teacher, float* __restrict__ wall){
  int idx = blockIdx.x * 256 + threadIdx.x;           // over 24*32*768
  int k  = idx % H_;
  int rb = idx / H_;                                  // t*32 + b
  int t = rb >> 5, b = rb & 31;
  int j = t >> 3, kk = t & 7;
  float v;
  if (kk == 0) v = dec[(b*3 + j)*H_ + k];
  else { int tok = teacher[(b*3 + j)*8 + kk - 1]; v = embed[(size_t)tok*H_ + k]; }
  wall[idx] = v;
}

// ---------------- h0 init: Hb[b][k] and Hq[k/4][b][k%4] ----------------
__global__ void k_init_h(const float* __restrict__ hidden, float* __restrict__ Hq, float* __restrict__ Hb){
  int idx = blockIdx.x * 256 + threadIdx.x;           // over 32*768
  int b = idx / H_, k = idx % H_;
  float v = hidden[idx];
  Hb[idx] = v;
  Hq[((k >> 2)*B_ + b)*4 + (k & 3)] = v;
}

// ---------------- fp32 GEMM (NT) + bias:  gi = wall * wih^T + bih ----------------
// M=768, N=2304, K=768
__global__ __launch_bounds__(256) void k_gi_gemm(const float* __restrict__ A, const float* __restrict__ Bm,
                                                 const float* __restrict__ bias, float* __restrict__ C){
  __shared__ float As[16][68];
  __shared__ float Bs[16][68];
  const int tid = threadIdx.x;
  const int tx = tid & 15, ty = tid >> 4;
  const int m0 = blockIdx.x * 64, n0 = blockIdx.y * 64;
  const int r = tid >> 2, kq = tid & 3;
  float acc[4][4] = {};
  for (int k0 = 0; k0 < 768; k0 += 16){
    float4 av = *(const float4*)&A [(size_t)(m0 + r)*768 + k0 + kq*4];
    float4 bv = *(const float4*)&Bm[(size_t)(n0 + r)*768 + k0 + kq*4];
    __syncthreads();
    As[kq*4+0][r] = av.x; As[kq*4+1][r] = av.y; As[kq*4+2][r] = av.z; As[kq*4+3][r] = av.w;
    Bs[kq*4+0][r] = bv.x; Bs[kq*4+1][r] = bv.y; Bs[kq*4+2][r] = bv.z; Bs[kq*4+3][r] = bv.w;
    __syncthreads();
#pragma unroll
    for (int kk = 0; kk < 16; ++kk){
      float4 a4 = *(const float4*)&As[kk][ty*4];
      float4 b4 = *(const float4*)&Bs[kk][tx*4];
      float aa[4] = {a4.x, a4.y, a4.z, a4.w};
      float bb[4] = {b4.x, b4.y, b4.z, b4.w};
#pragma unroll
      for (int i = 0; i < 4; ++i)
#pragma unroll
        for (int j = 0; j < 4; ++j)
          acc[i][j] = fmaf(aa[i], bb[j], acc[i][j]);
    }
  }
#pragma unroll
  for (int i = 0; i < 4; ++i){
    int m = m0 + ty*4 + i;
#pragma unroll
    for (int j = 0; j < 4; ++j){
      int n = n0 + tx*4 + j;
      C[(size_t)m*H3 + n] = acc[i][j] + bias[n];
    }
  }
}

// ---------------- one GRU step (fused gh matmul + gates), fp32 ----------------
// grid 192 x 128 threads: thread = (b = tid&31, jj = tid>>5), j = blk*4+jj
__global__ __launch_bounds__(128) void k_gru(const float* __restrict__ Hq_t, const float* __restrict__ Hb_t,
                                             const float* __restrict__ gi_t, const float* __restrict__ whh,
                                             const float* __restrict__ bhh,
                                             float* __restrict__ Hq_n, float* __restrict__ Hb_n){
  const int b = threadIdx.x & 31, jj = threadIdx.x >> 5;
  const int j = blockIdx.x * 4 + jj;
  float aR = 0.f, aZ = 0.f, aN = 0.f;
  const float4* hq = (const float4*)Hq_t;                      // [192][32] float4
  const float4* wr = (const float4*)&whh[(size_t)(j       )*768];
  const float4* wz = (const float4*)&whh[(size_t)(768  + j)*768];
  const float4* wn = (const float4*)&whh[(size_t)(1536 + j)*768];
#pragma unroll 4
  for (int kq = 0; kq < 192; ++kq){
    float4 h4 = hq[kq*32 + b];
    float4 r4 = wr[kq], z4 = wz[kq], n4 = wn[kq];
    aR += h4.x*r4.x + h4.y*r4.y + h4.z*r4.z + h4.w*r4.w;
    aZ += h4.x*z4.x + h4.y*z4.y + h4.z*z4.z + h4.w*z4.w;
    aN += h4.x*n4.x + h4.y*n4.y + h4.z*n4.z + h4.w*n4.w;
  }
  aR += bhh[j]; aZ += bhh[768 + j]; aN += bhh[1536 + j];
  float ir = gi_t[b*H3 + j], iz = gi_t[b*H3 + 768 + j], inn = gi_t[b*H3 + 1536 + j];
  float rg = 1.f / (1.f + expf(-(ir + aR)));
  float zg = 1.f / (1.f + expf(-(iz + aZ)));
  float ng = tanhf(inn + rg * aN);
  float hp = Hb_t[b*768 + j];
  float hn = (1.f - zg)*ng + zg*hp;
  Hb_n[b*768 + j] = hn;
  Hq_n[((j >> 2)*32 + b)*4 + (j & 3)] = hn;
}

// ---------------- attn_e[t][b][s] = enc[b][s][:] . h[t+1][b][:]  (fp32) ----------------
// grid (32 b, 8 s-tiles of 64), 256 threads
__global__ __launch_bounds__(256) void k_attn(const float* __restrict__ enc, const float* __restrict__ Hb1,
                                              float* __restrict__ ae){
  __shared__ float Es[64*36];
  __shared__ float Ht[24*36];
  const int b = blockIdx.x, s0 = blockIdx.y * 64;
  const int tid = threadIdx.x;
  const int s_l = tid & 63, tq = tid >> 6;
  const int r = tid >> 2, kq = tid & 3;
  float acc[6] = {0.f,0.f,0.f,0.f,0.f,0.f};
  for (int k0 = 0; k0 < 768; k0 += 32){
    __syncthreads();
    float4 e0 = *(const float4*)&enc[(size_t)(b*512 + s0 + r)*768 + k0 + kq*8];
    float4 e1 = *(const float4*)&enc[(size_t)(b*512 + s0 + r)*768 + k0 + kq*8 + 4];
    *(float4*)&Es[r*36 + kq*8]     = e0;
    *(float4*)&Es[r*36 + kq*8 + 4] = e1;
    if (tid < 192){
      int t = tid >> 3, k4 = tid & 7;
      *(float4*)&Ht[t*36 + k4*4] = *(const float4*)&Hb1[(size_t)t*24576 + b*768 + k0 + k4*4];
    }
    __syncthreads();
#pragma unroll
    for (int k4 = 0; k4 < 8; ++k4){
      float4 e = *(const float4*)&Es[s_l*36 + k4*4];
#pragma unroll
      for (int i = 0; i < 6; ++i){
        float4 h4 = *(const float4*)&Ht[(tq*6 + i)*36 + k4*4];
        acc[i] += e.x*h4.x + e.y*h4.y + e.z*h4.z + e.w*h4.w;
      }
    }
  }
#pragma unroll
  for (int i = 0; i < 6; ++i)
    ae[(size_t)((tq*6 + i)*32 + b)*512 + s0 + s_l] = acc[i];
}

// ---------------- masked softmax over S=512, in place ----------------
__global__ __launch_bounds__(256) void k_attnsoft(const int* __restrict__ x, float* __restrict__ ae){
  const int row = blockIdx.x;            // t*32+b
  const int b = row & 31;
  const int tid = threadIdx.x;
  __shared__ float red[256];
  float v0 = ae[(size_t)row*512 + tid];
  float v1 = ae[(size_t)row*512 + 256 + tid];
  if (x[b*512 + tid]        == 0) v0 = -1e9f;
  if (x[b*512 + 256 + tid]  == 0) v1 = -1e9f;
  float m = fmaxf(v0, v1);
  red[tid] = m; __syncthreads();
  for (int off = 128; off; off >>= 1){ if (tid < off) red[tid] = fmaxf(red[tid], red[tid+off]); __syncthreads(); }
  float M = red[0]; __syncthreads();
  float e0 = __expf(v0 - M), e1 = __expf(v1 - M);
  red[tid] = e0 + e1; __syncthreads();
  for (int off = 128; off; off >>= 1){ if (tid < off) red[tid] += red[tid+off]; __syncthreads(); }
  float inv = 1.f / red[0];
  ae[(size_t)row*512 + tid]       = e0 * inv;
  ae[(size_t)row*512 + 256 + tid] = e1 * inv;
}

// ---------------- context[t][b][k] = sum_s ah[t][b][s] * enc[b][s][k] ----------------
// grid (32 b, 12 k-tiles of 64), 256 threads
__global__ __launch_bounds__(256) void k_ctx(const float* __restrict__ enc, const float* __restrict__ ah,
                                             float* __restrict__ ctx){
  const int b = blockIdx.x;
  const int k = blockIdx.y * 64 + (threadIdx.x & 63);
  const int tq = threadIdx.x >> 6;
  float acc[6] = {0.f,0.f,0.f,0.f,0.f,0.f};
  for (int s4 = 0; s4 < 512; s4 += 4){
    float e0 = enc[(size_t)(b*512 + s4 + 0)*768 + k];
    float e1 = enc[(size_t)(b*512 + s4 + 1)*768 + k];
    float e2 = enc[(size_t)(b*512 + s4 + 2)*768 + k];
    float e3 = enc[(size_t)(b*512 + s4 + 3)*768 + k];
#pragma unroll
    for (int i = 0; i < 6; ++i){
      float4 a4 = *(const float4*)&ah[(size_t)((tq*6 + i)*32 + b)*512 + s4];
      acc[i] = fmaf(a4.x, e0, acc[i]); acc[i] = fmaf(a4.y, e1, acc[i]);
      acc[i] = fmaf(a4.z, e2, acc[i]); acc[i] = fmaf(a4.w, e3, acc[i]);
    }
  }
#pragma unroll
  for (int i = 0; i < 6; ++i)
    ctx[(size_t)((tq*6 + i)*32 + b)*768 + k] = acc[i];
}

// ---------------- p_gen[t*32+b] = sigmoid([w,h,ctx] . wg + b) ----------------
__global__ __launch_bounds__(256) void k_pgen(const float* __restrict__ wall, const float* __restrict__ Hb1,
                                              const float* __restrict__ ctx, const float* __restrict__ wg,
                                              const float* __restrict__ wgb, float* __restrict__ pgen){
  const int wid = threadIdx.x >> 6, lane = threadIdx.x & 63;
  const int row = blockIdx.x * 4 + wid;  // t*32+b
  const int t = row >> 5, b = row & 31;
  float s = 0.f;
#pragma unroll
  for (int i = 0; i < 12; ++i){
    int k = lane + i*64;
    s += wall[(size_t)row*768 + k]           * wg[k];
    s += Hb1[(size_t)t*24576 + b*768 + k]    * wg[768 + k];
    s += ctx[(size_t)row*768 + k]            * wg[1536 + k];
  }
  for (int off = 32; off; off >>= 1) s += __shfl_down(s, off, 64);
  if (lane == 0) pgen[row] = 1.f / (1.f + expf(-(s + wgb[0])));
}

// ---------------- async global->LDS 16B helper ----------------
__device__ __forceinline__ void load_lds_16B(const void* g, void* l){
  auto gp = reinterpret_cast<const __attribute__((address_space(1))) unsigned int*>(
      reinterpret_cast<uintptr_t>(g));
  auto lp = reinterpret_cast<__attribute__((address_space(3))) unsigned int*>(
      reinterpret_cast<uintptr_t>(l));
  __builtin_amdgcn_global_load_lds(gp, lp, 16, 0, 0);
}

// ---------------- vocab logits GEMM: out[(b*24+t)*V + v] = h[t+1][b][:] . E[v][:]  (bf16 MFMA) ----------------
// A2: [768][768] bf16 (rows r = t*32+b), E2: [V][768] bf16.  grid (239 n-tiles, 6 m-tiles), 256 threads.
__global__ __launch_bounds__(256) void k_vgemm(const ushort_t* __restrict__ A2, const ushort_t* __restrict__ E2,
                                               float* __restrict__ out){
  __shared__ ushort_t ldsA[128*64];
  __shared__ ushort_t ldsB[128*64];
  const int ntile = blockIdx.x, mtile = blockIdx.y;
  const int tid = threadIdx.x;
  const int w = tid >> 6, lane = tid & 63;
  const int lrow = lane >> 3, lpos = lane & 7;
  const int wm = w >> 1, wn = w & 1;
  const int q = lane >> 4, fr = lane & 15;
  f32x4 acc[4][4];
  f32x4 zero = {0.f, 0.f, 0.f, 0.f};
#pragma unroll
  for (int a = 0; a < 4; ++a)
#pragma unroll
    for (int c = 0; c < 4; ++c) acc[a][c] = zero;

  for (int k0 = 0; k0 < 768; k0 += 64){
    __syncthreads();
#pragma unroll
    for (int i = 0; i < 4; ++i){
      int row = w*32 + i*8 + lrow;          // 0..127
      int c   = lpos ^ (row & 7);           // XOR-swizzled source chunk
      const ushort_t* srcA = A2 + (size_t)(mtile*128 + row)*768 + k0 + c*8;
      int brow = ntile*128 + row; if (brow > V_ - 1) brow = V_ - 1;
      const ushort_t* srcB = E2 + (size_t)brow*768 + k0 + c*8;
      load_lds_16B(srcA, &ldsA[row*64 + lpos*8]);
      load_lds_16B(srcB, &ldsB[row*64 + lpos*8]);
    }
    __builtin_amdgcn_s_waitcnt(0);
    __syncthreads();
#pragma unroll
    for (int s = 0; s < 2; ++s){
      bf16x8 af[4], bfr[4];
#pragma unroll
      for (int mt = 0; mt < 4; ++mt){
        int row = wm*64 + mt*16 + fr;
        int ch = (s*4 + q) ^ (row & 7);
        af[mt] = *(const bf16x8*)&ldsA[row*64 + ch*8];
      }
#pragma unroll
      for (int nt = 0; nt < 4; ++nt){
        int row = wn*64 + nt*16 + fr;
        int ch = (s*4 + q) ^ (row & 7);
        bfr[nt] = *(const bf16x8*)&ldsB[row*64 + ch*8];
      }
#pragma unroll
      for (int mt = 0; mt < 4; ++mt)
#pragma unroll
        for (int nt = 0; nt < 4; ++nt)
          acc[mt][nt] = __builtin_amdgcn_mfma_f32_16x16x32_bf16(af[mt], bfr[nt], acc[mt][nt], 0, 0, 0);
    }
  }
  // epilogue: C/D layout col=lane&15, row=quad*4+reg
#pragma unroll
  for (int mt = 0; mt < 4; ++mt){
#pragma unroll
    for (int nt = 0; nt < 4; ++nt){
      int gn = ntile*128 + wn*64 + nt*16 + fr;
      if (gn >= V_) continue;
#pragma unroll
      for (int rg = 0; rg < 4; ++rg){
        int gm = mtile*128 + wm*64 + mt*16 + q*4 + rg;   // A row = t*32+b
        int t = gm >> 5, b = gm & 31;
        out[(size_t)(b*24 + t)*V_ + gn] = acc[mt][nt][rg];
      }
    }
  }
}

// ---------------- vocab softmax (online) * p_gen, in place on d_out ----------------
__global__ __launch_bounds__(256) void k_vsoft(float* __restrict__ out, const float* __restrict__ pgen){
  const int row = blockIdx.x;            // b*24+t
  const int b = row / 24, t = row % 24;
  const float pg = pgen[t*32 + b];
  const int tid = threadIdx.x;
  float* rp = out + (size_t)row * V_;
  float m = -3.0e38f, s = 0.f;
  for (int i = tid; i < V_; i += 256){
    float v = rp[i];
    float nm = fmaxf(m, v);
    s = s * __expf(m - nm) + __expf(v - nm);
    m = nm;
  }
  __shared__ float rm[256], rs[256];
  rm[tid] = m; rs[tid] = s; __syncthreads();
  for (int off = 128; off; off >>= 1){
    if (tid < off){
      float m2 = rm[tid+off], s2 = rs[tid+off];
      float nm = fmaxf(rm[tid], m2);
      rs[tid] = rs[tid]*__expf(rm[tid]-nm) + s2*__expf(m2-nm);
      rm[tid] = nm;
    }
    __syncthreads();
  }
  const float M = rm[0], inv = pg / rs[0];
  for (int i = tid; i < V_; i += 256){
    rp[i] = __expf(rp[i] - M) * inv;
  }
}

// ---------------- scatter copy-distribution: out[(b*24+t)*V + x[b][s]] += (1-pg)*ah ----------------
__global__ void k_scatter(const float* __restrict__ ah, const float* __restrict__ pgen,
                          const int* __restrict__ x, float* __restrict__ out){
  int idx = blockIdx.x * 256 + threadIdx.x;       // over 24*32*512
  int s = idx & 511;
  int row = idx >> 9;                              // t*32+b
  int t = row >> 5, b = row & 31;
  float val = ah[idx] * (1.f - pgen[row]);
  int col = x[b*512 + s];
  atomicAdd(&out[(size_t)(b*24 + t)*V_ + col], val);
}

extern "C" void kernel_launch(void* const* d_in, const int* in_sizes, int n_in,
                              void* d_out, int out_size, void* d_ws, size_t ws_size,
                              hipStream_t stream){
  (void)in_sizes; (void)n_in; (void)out_size; (void)ws_size;
  const int*   x      = (const int*)  d_in[0];
  const float* dec    = (const float*)d_in[1];
  const float* enc    = (const float*)d_in[2];
  const float* hidden = (const float*)d_in[3];
  const int*   teach  = (const int*)  d_in[4];
  const float* embed  = (const float*)d_in[5];
  const float* wih    = (const float*)d_in[6];
  const float* whh    = (const float*)d_in[7];
  const float* bih    = (const float*)d_in[8];
  const float* bhh    = (const float*)d_in[9];
  const float* wg     = (const float*)d_in[10];
  const float* wgb    = (const float*)d_in[11];
  float* out = (float*)d_out;

  char* p = (char*)d_ws;
  auto alloc = [&](size_t bytes){ void* r = (void*)p; p += (bytes + 255) & ~(size_t)255; return r; };
  ushort_t* E2  = (ushort_t*)alloc((size_t)V_ * H_ * 2);            // 46.9 MB
  ushort_t* A2  = (ushort_t*)alloc((size_t)768 * 768 * 2);          // 1.2 MB
  float* wall   = (float*)alloc((size_t)NT_ * B_ * H_ * 4);         // 2.4 MB
  float* Hb     = (float*)alloc((size_t)(NT_+1) * B_ * H_ * 4);     // 2.5 MB
  float* Hq     = (float*)alloc((size_t)(NT_+1) * B_ * H_ * 4);     // 2.5 MB
  float* gi     = (float*)alloc((size_t)NT_ * B_ * H3 * 4);         // 7.1 MB
  float* ae     = (float*)alloc((size_t)NT_ * B_ * S_ * 4);         // 1.6 MB
  float* ctx    = (float*)alloc((size_t)NT_ * B_ * H_ * 4);         // 2.4 MB
  float* pgen   = (float*)alloc(768 * 4);

  // Phase 0: precompute
  k_cast_bf16<<<(V_*H_/4 + 255)/256, 256, 0, stream>>>(embed, E2, V_*H_/4);
  k_build_wall<<<(NT_*B_*H_)/256, 256, 0, stream>>>(dec, embed, teach, wall);
  k_init_h<<<(B_*H_)/256, 256, 0, stream>>>(hidden, Hq, Hb);
  k_gi_gemm<<<dim3(12, 36), 256, 0, stream>>>(wall, wih, bih, gi);

  // Phase 1: sequential GRU (24 steps)
  for (int t = 0; t < NT_; ++t){
    k_gru<<<192, 128, 0, stream>>>(Hq + (size_t)t*24576, Hb + (size_t)t*24576,
                                   gi + (size_t)t*B_*H3, whh, bhh,
                                   Hq + (size_t)(t+1)*24576, Hb + (size_t)(t+1)*24576);
  }

  // Phase 2: batched attention + pointer-gen
  k_cast_bf16<<<(768*768/4 + 255)/256, 256, 0, stream>>>(Hb + 24576, A2, 768*768/4);
  k_attn<<<dim3(32, 8), 256, 0, stream>>>(enc, Hb + 24576, ae);
  k_attnsoft<<<768, 256, 0, stream>>>(x, ae);
  k_ctx<<<dim3(32, 12), 256, 0, stream>>>(enc, ae, ctx);
  k_pgen<<<192, 256, 0, stream>>>(wall, Hb + 24576, ctx, wg, wgb, pgen);

  // Phase 3: vocab distribution
  k_vgemm<<<dim3(239, 6), 256, 0, stream>>>(A2, E2, out);
  k_vsoft<<<768, 256, 0, stream>>>(out, pgen);
  k_scatter<<<(NT_*B_*S_)/256, 256, 0, stream>>>(ae, pgen, x, out);
}

// Round 2
// 950.942 us; speedup vs baseline: 1.4026x; 1.4026x over previous
//
#include <hip/hip_runtime.h>
#include <cstdint>

#define B_  32
#define S_  512
#define H_  768
#define V_  30522
#define NT_ 24          // N_UPDATE * MAX_LEN sequential steps
#define H3  2304

typedef unsigned short ushort_t;
typedef __attribute__((ext_vector_type(8))) short bf16x8;
typedef __attribute__((ext_vector_type(4))) float f32x4;

__device__ __forceinline__ ushort_t f2bf(float f){
  union { float f; unsigned u; } v; v.f = f;
  unsigned r = v.u + 0x7fffu + ((v.u >> 16) & 1u);
  return (ushort_t)(r >> 16);
}

// ---------------- fp32 -> bf16 cast (vector x4) ----------------
__global__ void k_cast_bf16(const float* __restrict__ src, ushort_t* __restrict__ dst, int n4){
  int i = blockIdx.x * 256 + threadIdx.x;
  if (i >= n4) return;
  float4 v = ((const float4*)src)[i];
  uint2 o;
  o.x = (unsigned)f2bf(v.x) | ((unsigned)f2bf(v.y) << 16);
  o.y = (unsigned)f2bf(v.z) | ((unsigned)f2bf(v.w) << 16);
  ((uint2*)dst)[i] = o;
}

// ---------------- build GRU inputs W_all[t][b][k] ----------------
__global__ void k_build_wall(const float* __restrict__ dec, const float* __restrict__ embed,
                             const int* __restrict__ teacher, float* __restrict__ wall){
  int idx = blockIdx.x * 256 + threadIdx.x;           // over 24*32*768
  int k  = idx % H_;
  int rb = idx / H_;                                  // t*32 + b
  int t = rb >> 5, b = rb & 31;
  int j = t >> 3, kk = t & 7;
  float v;
  if (kk == 0) v = dec[(b*3 + j)*H_ + k];
  else { int tok = teacher[(b*3 + j)*8 + kk - 1]; v = embed[(size_t)tok*H_ + k]; }
  wall[idx] = v;
}

// ---------------- h0 init: Hb[b][k] and Hq[k/4][b][k%4] ----------------
__global__ void k_init_h(const float* __restrict__ hidden, float* __restrict__ Hq, float* __restrict__ Hb){
  int idx = blockIdx.x * 256 + threadIdx.x;           // over 32*768
  int b = idx / H_, k = idx % H_;
  float v = hidden[idx];
  Hb[idx] = v;
  Hq[((k >> 2)*B_ + b)*4 + (k & 3)] = v;
}

// ---------------- fp32 GEMM (NT) + bias:  gi = wall * wih^T + bih ----------------
// M=768, N=2304, K=768
__global__ __launch_bounds__(256) void k_gi_gemm(const float* __restrict__ A, const float* __restrict__ Bm,
                                                 const float* __restrict__ bias, float* __restrict__ C){
  __shared__ float As[16][68];
  __shared__ float Bs[16][68];
  const int tid = threadIdx.x;
  const int tx = tid & 15, ty = tid >> 4;
  const int m0 = blockIdx.x * 64, n0 = blockIdx.y * 64;
  const int r = tid >> 2, kq = tid & 3;
  float acc[4][4] = {};
  for (int k0 = 0; k0 < 768; k0 += 16){
    float4 av = *(const float4*)&A [(size_t)(m0 + r)*768 + k0 + kq*4];
    float4 bv = *(const float4*)&Bm[(size_t)(n0 + r)*768 + k0 + kq*4];
    __syncthreads();
    As[kq*4+0][r] = av.x; As[kq*4+1][r] = av.y; As[kq*4+2][r] = av.z; As[kq*4+3][r] = av.w;
    Bs[kq*4+0][r] = bv.x; Bs[kq*4+1][r] = bv.y; Bs[kq*4+2][r] = bv.z; Bs[kq*4+3][r] = bv.w;
    __syncthreads();
#pragma unroll
    for (int kk = 0; kk < 16; ++kk){
      float4 a4 = *(const float4*)&As[kk][ty*4];
      float4 b4 = *(const float4*)&Bs[kk][tx*4];
      float aa[4] = {a4.x, a4.y, a4.z, a4.w};
      float bb[4] = {b4.x, b4.y, b4.z, b4.w};
#pragma unroll
      for (int i = 0; i < 4; ++i)
#pragma unroll
        for (int j = 0; j < 4; ++j)
          acc[i][j] = fmaf(aa[i], bb[j], acc[i][j]);
    }
  }
#pragma unroll
  for (int i = 0; i < 4; ++i){
    int m = m0 + ty*4 + i;
#pragma unroll
    for (int j = 0; j < 4; ++j){
      int n = n0 + tx*4 + j;
      C[(size_t)m*H3 + n] = acc[i][j] + bias[n];
    }
  }
}

// ---------------- one GRU step: one wave per output column j ----------------
// grid 768 x 64 threads. lane = khalf*32 + b. Weight rows are wave-broadcast
// (2 distinct 16B per inst); h comes from Hq [k/4][b][4] layout (coalesced).
__global__ __launch_bounds__(64) void k_gru(const float* __restrict__ Hq_t, const float* __restrict__ Hb_t,
                                            const float* __restrict__ gi_t, const float* __restrict__ whh,
                                            const float* __restrict__ bhh,
                                            float* __restrict__ Hq_n, float* __restrict__ Hb_n){
  const int j = blockIdx.x;                     // 0..767
  const int lane = threadIdx.x;
  const int khalf = lane >> 5, b = lane & 31;
  const float4* hqp = (const float4*)Hq_t + (size_t)khalf*96*32 + b;
  const float4* wr = (const float4*)&whh[(size_t)(       j)*768 + khalf*384];
  const float4* wz = (const float4*)&whh[(size_t)(768  + j)*768 + khalf*384];
  const float4* wn = (const float4*)&whh[(size_t)(1536 + j)*768 + khalf*384];
  float aR = 0.f, aZ = 0.f, aN = 0.f;
#pragma unroll 8
  for (int i = 0; i < 96; ++i){
    float4 h4 = hqp[(size_t)i*32];
    float4 r4 = wr[i], z4 = wz[i], n4 = wn[i];
    aR += h4.x*r4.x + h4.y*r4.y + h4.z*r4.z + h4.w*r4.w;
    aZ += h4.x*z4.x + h4.y*z4.y + h4.z*z4.z + h4.w*z4.w;
    aN += h4.x*n4.x + h4.y*n4.y + h4.z*n4.z + h4.w*n4.w;
  }
  aR += __shfl_xor(aR, 32, 64);
  aZ += __shfl_xor(aZ, 32, 64);
  aN += __shfl_xor(aN, 32, 64);
  if (lane < 32){
    aR += bhh[j]; aZ += bhh[768 + j]; aN += bhh[1536 + j];
    float ir = gi_t[b*H3 + j], iz = gi_t[b*H3 + 768 + j], inn = gi_t[b*H3 + 1536 + j];
    float rg = 1.f / (1.f + __expf(-(ir + aR)));
    float zg = 1.f / (1.f + __expf(-(iz + aZ)));
    float e2 = __expf(-2.f*(inn + rg * aN));
    float ng = (1.f - e2) / (1.f + e2);
    float hp = Hb_t[b*768 + j];
    float hn = (1.f - zg)*ng + zg*hp;
    Hb_n[b*768 + j] = hn;
    Hq_n[((j >> 2)*32 + b)*4 + (j & 3)] = hn;
  }
}

// ---------------- attn_e[t][b][s] = enc[b][s][:] . h[t+1][b][:]  (fp32) ----------------
// grid (32 b, 8 s-tiles of 64), 256 threads
__global__ __launch_bounds__(256) void k_attn(const float* __restrict__ enc, const float* __restrict__ Hb1,
                                              float* __restrict__ ae){
  __shared__ float Es[64*36];
  __shared__ float Ht[24*36];
  const int b = blockIdx.x, s0 = blockIdx.y * 64;
  const int tid = threadIdx.x;
  const int s_l = tid & 63, tq = tid >> 6;
  const int r = tid >> 2, kq = tid & 3;
  float acc[6] = {0.f,0.f,0.f,0.f,0.f,0.f};
  for (int k0 = 0; k0 < 768; k0 += 32){
    __syncthreads();
    float4 e0 = *(const float4*)&enc[(size_t)(b*512 + s0 + r)*768 + k0 + kq*8];
    float4 e1 = *(const float4*)&enc[(size_t)(b*512 + s0 + r)*768 + k0 + kq*8 + 4];
    *(float4*)&Es[r*36 + kq*8]     = e0;
    *(float4*)&Es[r*36 + kq*8 + 4] = e1;
    if (tid < 192){
      int t = tid >> 3, k4 = tid & 7;
      *(float4*)&Ht[t*36 + k4*4] = *(const float4*)&Hb1[(size_t)t*24576 + b*768 + k0 + k4*4];
    }
    __syncthreads();
#pragma unroll
    for (int k4 = 0; k4 < 8; ++k4){
      float4 e = *(const float4*)&Es[s_l*36 + k4*4];
#pragma unroll
      for (int i = 0; i < 6; ++i){
        float4 h4 = *(const float4*)&Ht[(tq*6 + i)*36 + k4*4];
        acc[i] += e.x*h4.x + e.y*h4.y + e.z*h4.z + e.w*h4.w;
      }
    }
  }
#pragma unroll
  for (int i = 0; i < 6; ++i)
    ae[(size_t)((tq*6 + i)*32 + b)*512 + s0 + s_l] = acc[i];
}

// ---------------- masked softmax over S=512, in place ----------------
__global__ __launch_bounds__(256) void k_attnsoft(const int* __restrict__ x, float* __restrict__ ae){
  const int row = blockIdx.x;            // t*32+b
  const int b = row & 31;
  const int tid = threadIdx.x;
  __shared__ float red[256];
  float v0 = ae[(size_t)row*512 + tid];
  float v1 = ae[(size_t)row*512 + 256 + tid];
  if (x[b*512 + tid]        == 0) v0 = -1e9f;
  if (x[b*512 + 256 + tid]  == 0) v1 = -1e9f;
  float m = fmaxf(v0, v1);
  red[tid] = m; __syncthreads();
  for (int off = 128; off; off >>= 1){ if (tid < off) red[tid] = fmaxf(red[tid], red[tid+off]); __syncthreads(); }
  float M = red[0]; __syncthreads();
  float e0 = __expf(v0 - M), e1 = __expf(v1 - M);
  red[tid] = e0 + e1; __syncthreads();
  for (int off = 128; off; off >>= 1){ if (tid < off) red[tid] += red[tid+off]; __syncthreads(); }
  float inv = 1.f / red[0];
  ae[(size_t)row*512 + tid]       = e0 * inv;
  ae[(size_t)row*512 + 256 + tid] = e1 * inv;
}

// ---------------- context[t][b][k] = sum_s ah[t][b][s] * enc[b][s][k] ----------------
// grid (32 b, 12 k-tiles of 64), 256 threads
__global__ __launch_bounds__(256) void k_ctx(const float* __restrict__ enc, const float* __restrict__ ah,
                                             float* __restrict__ ctx){
  const int b = blockIdx.x;
  const int k = blockIdx.y * 64 + (threadIdx.x & 63);
  const int tq = threadIdx.x >> 6;
  float acc[6] = {0.f,0.f,0.f,0.f,0.f,0.f};
  for (int s4 = 0; s4 < 512; s4 += 4){
    float e0 = enc[(size_t)(b*512 + s4 + 0)*768 + k];
    float e1 = enc[(size_t)(b*512 + s4 + 1)*768 + k];
    float e2 = enc[(size_t)(b*512 + s4 + 2)*768 + k];
    float e3 = enc[(size_t)(b*512 + s4 + 3)*768 + k];
#pragma unroll
    for (int i = 0; i < 6; ++i){
      float4 a4 = *(const float4*)&ah[(size_t)((tq*6 + i)*32 + b)*512 + s4];
      acc[i] = fmaf(a4.x, e0, acc[i]); acc[i] = fmaf(a4.y, e1, acc[i]);
      acc[i] = fmaf(a4.z, e2, acc[i]); acc[i] = fmaf(a4.w, e3, acc[i]);
    }
  }
#pragma unroll
  for (int i = 0; i < 6; ++i)
    ctx[(size_t)((tq*6 + i)*32 + b)*768 + k] = acc[i];
}

// ---------------- p_gen[t*32+b] = sigmoid([w,h,ctx] . wg + b) ----------------
__global__ __launch_bounds__(256) void k_pgen(const float* __restrict__ wall, const float* __restrict__ Hb1,
                                              const float* __restrict__ ctx, const float* __restrict__ wg,
                                              const float* __restrict__ wgb, float* __restrict__ pgen){
  const int wid = threadIdx.x >> 6, lane = threadIdx.x & 63;
  const int row = blockIdx.x * 4 + wid;  // t*32+b
  const int t = row >> 5, b = row & 31;
  float s = 0.f;
#pragma unroll
  for (int i = 0; i < 12; ++i){
    int k = lane + i*64;
    s += wall[(size_t)row*768 + k]           * wg[k];
    s += Hb1[(size_t)t*24576 + b*768 + k]    * wg[768 + k];
    s += ctx[(size_t)row*768 + k]            * wg[1536 + k];
  }
  for (int off = 32; off; off >>= 1) s += __shfl_down(s, off, 64);
  if (lane == 0) pgen[row] = 1.f / (1.f + expf(-(s + wgb[0])));
}

// ---------------- async global->LDS 16B helper ----------------
__device__ __forceinline__ void load_lds_16B(const void* g, void* l){
  auto gp = reinterpret_cast<const __attribute__((address_space(1))) unsigned int*>(
      reinterpret_cast<uintptr_t>(g));
  auto lp = reinterpret_cast<__attribute__((address_space(3))) unsigned int*>(
      reinterpret_cast<uintptr_t>(l));
  __builtin_amdgcn_global_load_lds(gp, lp, 16, 0, 0);
}

// ---------------- vocab logits GEMM: out[(b*24+t)*V + v] = h[t+1][b][:] . E[v][:]  (bf16 MFMA) ----------------
// A2: [768][768] bf16 (rows r = t*32+b), E2: [V][768] bf16.  grid (239 n-tiles, 6 m-tiles), 256 threads.
__global__ __launch_bounds__(256) void k_vgemm(const ushort_t* __restrict__ A2, const ushort_t* __restrict__ E2,
                                               float* __restrict__ out){
  __shared__ ushort_t ldsA[128*64];
  __shared__ ushort_t ldsB[128*64];
  const int ntile = blockIdx.x, mtile = blockIdx.y;
  const int tid = threadIdx.x;
  const int w = tid >> 6, lane = tid & 63;
  const int lrow = lane >> 3, lpos = lane & 7;
  const int wm = w >> 1, wn = w & 1;
  const int q = lane >> 4, fr = lane & 15;
  f32x4 acc[4][4];
  f32x4 zero = {0.f, 0.f, 0.f, 0.f};
#pragma unroll
  for (int a = 0; a < 4; ++a)
#pragma unroll
    for (int c = 0; c < 4; ++c) acc[a][c] = zero;

  for (int k0 = 0; k0 < 768; k0 += 64){
    __syncthreads();
#pragma unroll
    for (int i = 0; i < 4; ++i){
      int row = w*32 + i*8 + lrow;          // 0..127
      int c   = lpos ^ (row & 7);           // XOR-swizzled source chunk
      const ushort_t* srcA = A2 + (size_t)(mtile*128 + row)*768 + k0 + c*8;
      int brow = ntile*128 + row; if (brow > V_ - 1) brow = V_ - 1;
      const ushort_t* srcB = E2 + (size_t)brow*768 + k0 + c*8;
      load_lds_16B(srcA, &ldsA[row*64 + lpos*8]);
      load_lds_16B(srcB, &ldsB[row*64 + lpos*8]);
    }
    __builtin_amdgcn_s_waitcnt(0);
    __syncthreads();
#pragma unroll
    for (int s = 0; s < 2; ++s){
      bf16x8 af[4], bfr[4];
#pragma unroll
      for (int mt = 0; mt < 4; ++mt){
        int row = wm*64 + mt*16 + fr;
        int ch = (s*4 + q) ^ (row & 7);
        af[mt] = *(const bf16x8*)&ldsA[row*64 + ch*8];
      }
#pragma unroll
      for (int nt = 0; nt < 4; ++nt){
        int row = wn*64 + nt*16 + fr;
        int ch = (s*4 + q) ^ (row & 7);
        bfr[nt] = *(const bf16x8*)&ldsB[row*64 + ch*8];
      }
#pragma unroll
      for (int mt = 0; mt < 4; ++mt)
#pragma unroll
        for (int nt = 0; nt < 4; ++nt)
          acc[mt][nt] = __builtin_amdgcn_mfma_f32_16x16x32_bf16(af[mt], bfr[nt], acc[mt][nt], 0, 0, 0);
    }
  }
  // epilogue: C/D layout col=lane&15, row=quad*4+reg
#pragma unroll
  for (int mt = 0; mt < 4; ++mt){
#pragma unroll
    for (int nt = 0; nt < 4; ++nt){
      int gn = ntile*128 + wn*64 + nt*16 + fr;
      if (gn >= V_) continue;
#pragma unroll
      for (int rg = 0; rg < 4; ++rg){
        int gm = mtile*128 + wm*64 + mt*16 + q*4 + rg;   // A row = t*32+b
        int t = gm >> 5, b = gm & 31;
        out[(size_t)(b*24 + t)*V_ + gn] = acc[mt][nt][rg];
      }
    }
  }
}

// ---------------- vocab softmax (online) * p_gen, in place on d_out ----------------
// 512 threads, float4 loads, shuffle + LDS (m,s) merge.  V = 7630 float4 + 2 tail floats.
__global__ __launch_bounds__(512) void k_vsoft(float* __restrict__ out, const float* __restrict__ pgen){
  const int row = blockIdx.x;            // b*24+t
  const int b = row / 24, t = row % 24;
  const float pg = pgen[t*32 + b];
  const int tid = threadIdx.x;
  float* rp = out + (size_t)row * V_;
  const float4* rp4 = (const float4*)rp;
  float m = -3.0e38f, s = 0.f;
  for (int i = tid; i < 7630; i += 512){
    float4 v = rp4[i];
    float vm = fmaxf(fmaxf(v.x, v.y), fmaxf(v.z, v.w));
    float vs = __expf(v.x - vm) + __expf(v.y - vm) + __expf(v.z - vm) + __expf(v.w - vm);
    float nm = fmaxf(m, vm);
    s = s * __expf(m - nm) + vs * __expf(vm - nm);
    m = nm;
  }
  if (tid < 2){
    float v = rp[30520 + tid];
    float nm = fmaxf(m, v);
    s = s * __expf(m - nm) + __expf(v - nm);
    m = nm;
  }
  // wave reduce
#pragma unroll
  for (int off = 1; off < 64; off <<= 1){
    float m2 = __shfl_xor(m, off, 64), s2 = __shfl_xor(s, off, 64);
    float nm = fmaxf(m, m2);
    s = s*__expf(m - nm) + s2*__expf(m2 - nm);
    m = nm;
  }
  __shared__ float rm[8], rs[8];
  const int wid = tid >> 6;
  if ((tid & 63) == 0){ rm[wid] = m; rs[wid] = s; }
  __syncthreads();
  if (tid == 0){
    float M = rm[0], S = rs[0];
#pragma unroll
    for (int i = 1; i < 8; ++i){
      float m2 = rm[i], s2 = rs[i];
      float nm = fmaxf(M, m2);
      S = S*__expf(M - nm) + s2*__expf(m2 - nm);
      M = nm;
    }
    rm[0] = M; rs[0] = pg / S;
  }
  __syncthreads();
  const float M = rm[0], inv = rs[0];
  for (int i = tid; i < 7630; i += 512){
    float4 v = rp4[i];
    v.x = __expf(v.x - M) * inv;
    v.y = __expf(v.y - M) * inv;
    v.z = __expf(v.z - M) * inv;
    v.w = __expf(v.w - M) * inv;
    ((float4*)rp)[i] = v;
  }
  if (tid < 2) rp[30520 + tid] = __expf(rp[30520 + tid] - M) * inv;
}

// ---------------- scatter copy-distribution: out[(b*24+t)*V + x[b][s]] += (1-pg)*ah ----------------
__global__ void k_scatter(const float* __restrict__ ah, const float* __restrict__ pgen,
                          const int* __restrict__ x, float* __restrict__ out){
  int idx = blockIdx.x * 256 + threadIdx.x;       // over 24*32*512
  int s = idx & 511;
  int row = idx >> 9;                              // t*32+b
  int t = row >> 5, b = row & 31;
  float val = ah[idx] * (1.f - pgen[row]);
  int col = x[b*512 + s];
  atomicAdd(&out[(size_t)(b*24 + t)*V_ + col], val);
}

extern "C" void kernel_launch(void* const* d_in, const int* in_sizes, int n_in,
                              void* d_out, int out_size, void* d_ws, size_t ws_size,
                              hipStream_t stream){
  (void)in_sizes; (void)n_in; (void)out_size; (void)ws_size;
  const int*   x      = (const int*)  d_in[0];
  const float* dec    = (const float*)d_in[1];
  const float* enc    = (const float*)d_in[2];
  const float* hidden = (const float*)d_in[3];
  const int*   teach  = (const int*)  d_in[4];
  const float* embed  = (const float*)d_in[5];
  const float* wih    = (const float*)d_in[6];
  const float* whh    = (const float*)d_in[7];
  const float* bih    = (const float*)d_in[8];
  const float* bhh    = (const float*)d_in[9];
  const float* wg     = (const float*)d_in[10];
  const float* wgb    = (const float*)d_in[11];
  float* out = (float*)d_out;

  char* p = (char*)d_ws;
  auto alloc = [&](size_t bytes){ void* r = (void*)p; p += (bytes + 255) & ~(size_t)255; return r; };
  ushort_t* E2  = (ushort_t*)alloc((size_t)V_ * H_ * 2);            // 46.9 MB
  ushort_t* A2  = (ushort_t*)alloc((size_t)768 * 768 * 2);          // 1.2 MB
  float* wall   = (float*)alloc((size_t)NT_ * B_ * H_ * 4);         // 2.4 MB
  float* Hb     = (float*)alloc((size_t)(NT_+1) * B_ * H_ * 4);     // 2.5 MB
  float* Hq     = (float*)alloc((size_t)(NT_+1) * B_ * H_ * 4);     // 2.5 MB
  float* gi     = (float*)alloc((size_t)NT_ * B_ * H3 * 4);         // 7.1 MB
  float* ae     = (float*)alloc((size_t)NT_ * B_ * S_ * 4);         // 1.6 MB
  float* ctx    = (float*)alloc((size_t)NT_ * B_ * H_ * 4);         // 2.4 MB
  float* pgen   = (float*)alloc(768 * 4);

  // Phase 0: precompute
  k_cast_bf16<<<(V_*H_/4 + 255)/256, 256, 0, stream>>>(embed, E2, V_*H_/4);
  k_build_wall<<<(NT_*B_*H_)/256, 256, 0, stream>>>(dec, embed, teach, wall);
  k_init_h<<<(B_*H_)/256, 256, 0, stream>>>(hidden, Hq, Hb);
  k_gi_gemm<<<dim3(12, 36), 256, 0, stream>>>(wall, wih, bih, gi);

  // Phase 1: sequential GRU (24 steps), one wave per output column
  for (int t = 0; t < NT_; ++t){
    k_gru<<<768, 64, 0, stream>>>(Hq + (size_t)t*24576, Hb + (size_t)t*24576,
                                  gi + (size_t)t*B_*H3, whh, bhh,
                                  Hq + (size_t)(t+1)*24576, Hb + (size_t)(t+1)*24576);
  }

  // Phase 2: batched attention + pointer-gen
  k_cast_bf16<<<(768*768/4 + 255)/256, 256, 0, stream>>>(Hb + 24576, A2, 768*768/4);
  k_attn<<<dim3(32, 8), 256, 0, stream>>>(enc, Hb + 24576, ae);
  k_attnsoft<<<768, 256, 0, stream>>>(x, ae);
  k_ctx<<<dim3(32, 12), 256, 0, stream>>>(enc, ae, ctx);
  k_pgen<<<192, 256, 0, stream>>>(wall, Hb + 24576, ctx, wg, wgb, pgen);

  // Phase 3: vocab distribution
  k_vgemm<<<dim3(239, 6), 256, 0, stream>>>(A2, E2, out);
  k_vsoft<<<768, 512, 0, stream>>>(out, pgen);
  k_scatter<<<(NT_*B_*S_)/256, 256, 0, stream>>>(ae, pgen, x, out);
}